// Round 1
// baseline (55.081 us; speedup 1.0000x reference)
//
#include <hip/hip_runtime.h>

// Problem constants (fixed by setup_inputs): (16,3,512,512) f32, PATCH=16
constexpr int IMG         = 512;
constexpr int PLANES      = 48;                 // 16 * 3
constexpr int NPATCH      = 1024;               // (512/16)^2 per plane
constexpr int TOTAL_PATCH = PLANES * NPATCH;    // 49152
constexpr int PLANE_ELEMS = IMG * IMG;          // 262144
constexpr long long TOTAL_ELEMS = (long long)PLANES * PLANE_ELEMS; // 12582912
constexpr float  EPS = 1e-6f;

__device__ __forceinline__ float waveReduceSum(float v) {
#pragma unroll
    for (int m = 1; m < 64; m <<= 1)
        v += __shfl_xor(v, m, 64);
    return v;
}

// One wave (64 lanes) per patch; 4 patches per 256-thread block.
__global__ __launch_bounds__(256) void patch_main(
    const float* __restrict__ p0,   // "out" (target)
    const float* __restrict__ p1,   // x1
    const float* __restrict__ p2,   // x2
    float* __restrict__ dout,       // [0]=loss, [1..]=w1_img, then w2_img
    float* __restrict__ partial)    // per-block loss partial sums
{
    const int lane  = threadIdx.x & 63;
    const int wv    = threadIdx.x >> 6;
    const int patch = blockIdx.x * 4 + wv;      // 0..49151
    const int plane = patch >> 10;              // b*3 + c
    const int n     = patch & 1023;             // patch index in plane
    const int pi    = n >> 5;                   // patch-grid row
    const int pj    = n & 31;                   // patch-grid col

    // lane -> (row r in patch, 4-col group)
    const int r  = lane >> 2;
    const int c4 = (lane & 3) << 2;

    const size_t ibase = (size_t)plane * PLANE_ELEMS
                       + (size_t)(pi * 16 + r) * IMG
                       + (size_t)(pj * 16 + c4);

    const float4 a = *(const float4*)(p0 + ibase);
    const float4 b = *(const float4*)(p1 + ibase);
    const float4 c = *(const float4*)(p2 + ibase);

    // mu1 = mean(patch1)
    float s = (b.x + b.y) + (b.z + b.w);
    s = waveReduceSum(s);
    const float mu = s * (1.0f / 256.0f);

    // sd1 around mu1, sd2 ALSO around mu1 (faithful to reference)
    float bx = b.x - mu, by = b.y - mu, bz = b.z - mu, bw = b.w - mu;
    float cx = c.x - mu, cy = c.y - mu, cz = c.z - mu, cw = c.w - mu;
    float d1 = (bx*bx + by*by) + (bz*bz + bw*bw);
    float d2 = (cx*cx + cy*cy) + (cz*cz + cw*cw);
    d1 = waveReduceSum(d1);
    d2 = waveReduceSum(d2);

    const float sd1 = sqrtf(d1 * (1.0f / 256.0f));
    const float sd2 = sqrtf(d2 * (1.0f / 256.0f));
    const float denom = sd1 + sd2 + EPS;
    const float w1 = sd1 / denom;
    const float w2 = sd2 / denom;

    // loss contribution: (p0 - (w1*p1 + w2*p2))^2
    float e0 = a.x - (w1 * b.x + w2 * c.x);
    float e1 = a.y - (w1 * b.y + w2 * c.y);
    float e2 = a.z - (w1 * b.z + w2 * c.z);
    float e3 = a.w - (w1 * b.w + w2 * c.w);
    float l = (e0*e0 + e1*e1) + (e2*e2 + e3*e3);
    l = waveReduceSum(l);

    // Broadcast weights: w_img flat index per plane is n*256 + p (plain reshape).
    // d_out + 1 is only 4B-aligned -> scalar stores (still contiguous 1KB/wave).
    float* __restrict__ w1o = dout + 1;
    float* __restrict__ w2o = dout + 1 + TOTAL_ELEMS;
    const size_t ob = (size_t)plane * PLANE_ELEMS + (size_t)n * 256 + (size_t)lane * 4;
#pragma unroll
    for (int k = 0; k < 4; ++k) w1o[ob + k] = w1;
#pragma unroll
    for (int k = 0; k < 4; ++k) w2o[ob + k] = w2;

    // Per-block loss partial (deterministic, no atomics)
    __shared__ float ls[4];
    if (lane == 0) ls[wv] = l;
    __syncthreads();
    if (threadIdx.x == 0)
        partial[blockIdx.x] = (ls[0] + ls[1]) + (ls[2] + ls[3]);
}

__global__ __launch_bounds__(256) void patch_reduce(
    const float* __restrict__ partial, float* __restrict__ dout)
{
    constexpr int NPART = TOTAL_PATCH / 4;  // 12288
    double s = 0.0;
    for (int i = threadIdx.x; i < NPART; i += 256)
        s += (double)partial[i];
#pragma unroll
    for (int m = 1; m < 64; m <<= 1)
        s += __shfl_xor(s, m, 64);
    __shared__ double sm[4];
    if ((threadIdx.x & 63) == 0) sm[threadIdx.x >> 6] = s;
    __syncthreads();
    if (threadIdx.x == 0)
        dout[0] = (float)(((sm[0] + sm[1]) + (sm[2] + sm[3])) / (double)TOTAL_ELEMS);
}

extern "C" void kernel_launch(void* const* d_in, const int* in_sizes, int n_in,
                              void* d_out, int out_size, void* d_ws, size_t ws_size,
                              hipStream_t stream) {
    const float* p0 = (const float*)d_in[0];   // out (target)
    const float* p1 = (const float*)d_in[1];   // x1
    const float* p2 = (const float*)d_in[2];   // x2
    float* dout    = (float*)d_out;
    float* partial = (float*)d_ws;             // 12288 floats = 48 KiB

    patch_main<<<TOTAL_PATCH / 4, 256, 0, stream>>>(p0, p1, p2, dout, partial);
    patch_reduce<<<1, 256, 0, stream>>>(partial, dout);
}

// Round 3
// 50.498 us; speedup vs baseline: 1.0908x; 1.0908x over previous
//
#include <hip/hip_runtime.h>

// Problem constants (fixed by setup_inputs): (16,3,512,512) f32, PATCH=16
constexpr int IMG         = 512;
constexpr int PLANES      = 48;                 // 16 * 3
constexpr int TOTAL_PATCH = PLANES * 1024;      // 49152
constexpr int PLANE_ELEMS = IMG * IMG;          // 262144
constexpr long long TOTAL_ELEMS = (long long)PLANES * PLANE_ELEMS; // 12582912
constexpr float  EPS = 1e-6f;
constexpr int PATCHES_PER_BLOCK = 8;            // 4 waves x 2 patches
constexpr int NBLOCKS = TOTAL_PATCH / PATCHES_PER_BLOCK;  // 6144

// ---- DPP wave64 reduction (gfx9 pattern): total lands in lane 63 ----
template <int CTRL, int ROW_MASK>
__device__ __forceinline__ float dpp_add(float v) {
    int x = __builtin_amdgcn_update_dpp(0, __float_as_int(v), CTRL, ROW_MASK, 0xF, false);
    return v + __int_as_float(x);
}
__device__ __forceinline__ float wave_total63(float v) {
    v = dpp_add<0x111, 0xF>(v);  // row_shr:1
    v = dpp_add<0x112, 0xF>(v);  // row_shr:2
    v = dpp_add<0x114, 0xF>(v);  // row_shr:4
    v = dpp_add<0x118, 0xF>(v);  // row_shr:8  -> lane15/31/47/63 = row sums
    v = dpp_add<0x142, 0xA>(v);  // row_bcast15 -> rows 1,3
    v = dpp_add<0x143, 0xC>(v);  // row_bcast31 -> rows 2,3; lane63 = total
    return v;
}
__device__ __forceinline__ float wave_allsum(float v) {
    v = wave_total63(v);
    return __int_as_float(__builtin_amdgcn_readlane(__float_as_int(v), 63));
}

__device__ __forceinline__ size_t in_base(int patch, int lane) {
    const int plane = patch >> 10;
    const int n     = patch & 1023;
    const int pi    = n >> 5, pj = n & 31;
    const int r     = lane >> 2, c4 = (lane & 3) << 2;
    return (size_t)plane * PLANE_ELEMS + (size_t)(pi * 16 + r) * IMG + (size_t)(pj * 16 + c4);
}

// Compute w1,w2 (all lanes) and loss partial total (valid in lane 63 only)
__device__ __forceinline__ void process_patch(const float4& a, const float4& b, const float4& c,
                                              float& w1, float& w2, float& loss63) {
    float s  = (b.x + b.y) + (b.z + b.w);
    const float mu = wave_allsum(s) * (1.0f / 256.0f);

    float bx = b.x - mu, by = b.y - mu, bz = b.z - mu, bw = b.w - mu;
    float cx = c.x - mu, cy = c.y - mu, cz = c.z - mu, cw = c.w - mu;
    float d1 = (bx*bx + by*by) + (bz*bz + bw*bw);
    float d2 = (cx*cx + cy*cy) + (cz*cz + cw*cw);
    d1 = wave_allsum(d1);
    d2 = wave_allsum(d2);

    const float sd1 = sqrtf(d1 * (1.0f / 256.0f));
    const float sd2 = sqrtf(d2 * (1.0f / 256.0f));
    const float denom = sd1 + sd2 + EPS;
    w1 = sd1 / denom;
    w2 = sd2 / denom;

    float e0 = a.x - (w1 * b.x + w2 * c.x);
    float e1 = a.y - (w1 * b.y + w2 * c.y);
    float e2 = a.z - (w1 * b.z + w2 * c.z);
    float e3 = a.w - (w1 * b.w + w2 * c.w);
    loss63 = wave_total63((e0*e0 + e1*e1) + (e2*e2 + e3*e3));
}

// Vectorized broadcast-store of a patch's weight image region (256 floats,
// misaligned by 1 float because d_out[0] is the loss scalar).
__device__ __forceinline__ void store_w(float* __restrict__ base, float w, int lane) {
    if (lane < 63) {
        float4 v = make_float4(w, w, w, w);
        *(float4*)(base + 3 + (lane << 2)) = v;     // 16B-aligned interior
    }
    if (lane < 4) base[lane == 3 ? 255 : lane] = w; // 3-float head + 1-float tail
}

__global__ __launch_bounds__(256) void patch_main(
    const float* __restrict__ p0, const float* __restrict__ p1, const float* __restrict__ p2,
    float* __restrict__ dout, float* __restrict__ partial)
{
    const int lane = threadIdx.x & 63;
    const int wv   = threadIdx.x >> 6;
    const int pA   = blockIdx.x * PATCHES_PER_BLOCK + wv * 2;
    const int pB   = pA + 1;

    const size_t iA = in_base(pA, lane);
    const size_t iB = in_base(pB, lane);

    // Issue all 6 loads up front for MLP
    const float4 aA = *(const float4*)(p0 + iA);
    const float4 bA = *(const float4*)(p1 + iA);
    const float4 cA = *(const float4*)(p2 + iA);
    const float4 aB = *(const float4*)(p0 + iB);
    const float4 bB = *(const float4*)(p1 + iB);
    const float4 cB = *(const float4*)(p2 + iB);

    float w1A, w2A, lA, w1B, w2B, lB;
    process_patch(aA, bA, cA, w1A, w2A, lA);
    process_patch(aB, bB, cB, w1B, w2B, lB);

    float* __restrict__ w1o = dout + 1;
    float* __restrict__ w2o = dout + 1 + TOTAL_ELEMS;
    const size_t obA = ((size_t)(pA >> 10)) * PLANE_ELEMS + (size_t)(pA & 1023) * 256;
    const size_t obB = ((size_t)(pB >> 10)) * PLANE_ELEMS + (size_t)(pB & 1023) * 256;
    store_w(w1o + obA, w1A, lane);
    store_w(w2o + obA, w2A, lane);
    store_w(w1o + obB, w1B, lane);
    store_w(w2o + obB, w2B, lane);

    // Per-block loss partial (deterministic, no atomics). lane 63 holds totals.
    __shared__ float ls[4];
    if (lane == 63) ls[wv] = lA + lB;
    __syncthreads();
    if (threadIdx.x == 0)
        partial[blockIdx.x] = (ls[0] + ls[1]) + (ls[2] + ls[3]);
}

__global__ __launch_bounds__(256) void patch_reduce(
    const float* __restrict__ partial, float* __restrict__ dout)
{
    constexpr int NPART = NBLOCKS;  // 6144
    double s = 0.0;
    for (int i = threadIdx.x; i < NPART; i += 256)
        s += (double)partial[i];
#pragma unroll
    for (int m = 1; m < 64; m <<= 1)
        s += __shfl_xor(s, m, 64);
    __shared__ double sm[4];
    if ((threadIdx.x & 63) == 0) sm[threadIdx.x >> 6] = s;
    __syncthreads();
    if (threadIdx.x == 0)
        dout[0] = (float)(((sm[0] + sm[1]) + (sm[2] + sm[3])) / (double)TOTAL_ELEMS);
}

extern "C" void kernel_launch(void* const* d_in, const int* in_sizes, int n_in,
                              void* d_out, int out_size, void* d_ws, size_t ws_size,
                              hipStream_t stream) {
    const float* p0 = (const float*)d_in[0];   // out (target)
    const float* p1 = (const float*)d_in[1];   // x1
    const float* p2 = (const float*)d_in[2];   // x2
    float* dout    = (float*)d_out;
    float* partial = (float*)d_ws;             // 6144 floats

    patch_main<<<NBLOCKS, 256, 0, stream>>>(p0, p1, p2, dout, partial);
    patch_reduce<<<1, 256, 0, stream>>>(partial, dout);
}